// Round 8
// baseline (301.129 us; speedup 1.0000x reference)
//
#include <hip/hip_runtime.h>
#include <hip/hip_bf16.h>

// Sparse MoE: T=2048, D=1024, E=8 routed (H=768, top-2) + shared GatedMLP (1536 hidden).
// R8: fc1/fc2 rebuilt as 128-thread (2-wave) blocks, wave tile 64x128 (12 ds_read per
// 32 MFMA), BK=32 double-buffered LDS (16KB/stage, 32KB total, ~4 blocks/CU), 2-way-free
// bank swizzle c^(r&3)^((r>>2)&3). convgate (conv+gate+zero-out) unchanged from R7.

typedef short bf16x8 __attribute__((ext_vector_type(8)));
typedef float f32x4 __attribute__((ext_vector_type(4)));

__device__ __forceinline__ unsigned short f2b(float f) {
    __hip_bfloat16 h = __float2bfloat16(f);
    return *reinterpret_cast<unsigned short*>(&h);
}

__device__ __forceinline__ void ldst16(const unsigned short* g, unsigned short* l) {
    __builtin_amdgcn_global_load_lds(
        (const __attribute__((address_space(1))) unsigned int*)g,
        (__attribute__((address_space(3))) unsigned int*)l, 16, 0, 0);
}

__device__ __forceinline__ void cvt8(const float* s, unsigned short* d, int j) {
    const float4* sp = reinterpret_cast<const float4*>(s) + (size_t)j * 2;
    float4 v0 = sp[0], v1 = sp[1];
    union { unsigned short u[8]; uint4 v; } o;
    o.u[0]=f2b(v0.x); o.u[1]=f2b(v0.y); o.u[2]=f2b(v0.z); o.u[3]=f2b(v0.w);
    o.u[4]=f2b(v1.x); o.u[5]=f2b(v1.y); o.u[6]=f2b(v1.z); o.u[7]=f2b(v1.w);
    *(reinterpret_cast<uint4*>(d) + j) = o.v;
}

// ------- merged: weight conversion (blocks 0..11519) + gate (blocks 11520..13567) -----
__global__ __launch_bounds__(256) void k_convgate(const float* __restrict__ x,
                                                  const float* __restrict__ gw,
                                                  const float* __restrict__ W1,
                                                  const float* __restrict__ Ws1,
                                                  const float* __restrict__ W2,
                                                  const float* __restrict__ Ws2,
                                                  unsigned short* __restrict__ xb,
                                                  unsigned short* __restrict__ W1b,
                                                  unsigned short* __restrict__ Ws1b,
                                                  unsigned short* __restrict__ W2b,
                                                  unsigned short* __restrict__ Ws2b,
                                                  int* __restrict__ tokslot,
                                                  float* __restrict__ wroute,
                                                  int* __restrict__ cnt,
                                                  float* __restrict__ out) {
    __shared__ float red[4][8];
    __shared__ float sc[8];
    const int b = blockIdx.x, tid = threadIdx.x;
    if (b < 11520) {
        int i = b * 256 + tid;
        if (i < 1572864)       cvt8(W1,  W1b,  i);
        else if (i < 1966080)  cvt8(Ws1, Ws1b, i - 1572864);
        else if (i < 2752512)  cvt8(W2,  W2b,  i - 1966080);
        else if (i < 2949120)  cvt8(Ws2, Ws2b, i - 2752512);
        return;
    }
    const int t = b - 11520;
    const int lane = tid & 63, w = tid >> 6;

    float4 v = reinterpret_cast<const float4*>(x + (size_t)t * 1024)[tid];
    union { unsigned short u[4]; } o;
    o.u[0]=f2b(v.x); o.u[1]=f2b(v.y); o.u[2]=f2b(v.z); o.u[3]=f2b(v.w);
    reinterpret_cast<ushort4*>(xb + (size_t)t * 1024)[tid] = *(ushort4*)o.u;

    float p[8];
    for (int e = 0; e < 8; e++) {
        float4 g = reinterpret_cast<const float4*>(gw + (size_t)e * 1024)[tid];
        p[e] = v.x*g.x + v.y*g.y + v.z*g.z + v.w*g.w;
    }
    for (int e = 0; e < 8; e++)
        for (int off = 32; off > 0; off >>= 1) p[e] += __shfl_down(p[e], off, 64);
    if (lane == 0)
        for (int e = 0; e < 8; e++) red[w][e] = p[e];
    __syncthreads();
    if (tid < 8) sc[tid] = red[0][tid] + red[1][tid] + red[2][tid] + red[3][tid];
    __syncthreads();
    if (tid == 0) {
        float m = sc[0];
        for (int e = 1; e < 8; e++) m = fmaxf(m, sc[e]);
        float ex[8], sum = 0.f;
        for (int e = 0; e < 8; e++) { ex[e] = expf(sc[e] - m); sum += ex[e]; }
        float inv = 1.f / sum;
        int i1 = 0;
        for (int e = 1; e < 8; e++) if (sc[e] > sc[i1]) i1 = e;
        int i2 = -1; float s2 = -1e30f;
        for (int e = 0; e < 8; e++) if (e != i1 && sc[e] > s2) { s2 = sc[e]; i2 = e; }
        int p1 = atomicAdd(&cnt[i1 * 16], 1);          // 64B-padded counters
        tokslot[i1 * 2048 + p1] = t; wroute[i1 * 2048 + p1] = ex[i1] * inv;
        int p2 = atomicAdd(&cnt[i2 * 16], 1);
        tokslot[i2 * 2048 + p2] = t; wroute[i2 * 2048 + p2] = ex[i2] * inv;
    }
    reinterpret_cast<float4*>(out + (size_t)t * 1024)[tid] = (float4){0.f, 0.f, 0.f, 0.f};
}

// ---------- fc1: 10 experts, block = 2 waves, tile M128 x 64 h-pairs, BK=32 dbuf ------
// Grid 864 = 72 mt x 12 ht. Slots: mt 0..31 = pseudo-shared (e=8,9), 32.. = routed.
// Bs rows 0..63 = y rows, 64..127 = g rows. Wave w covers tokens 64w..64w+63, all 64 h.
__global__ __launch_bounds__(128) void k_fc1u(const unsigned short* __restrict__ xb,
                                              const unsigned short* __restrict__ W1b,
                                              const unsigned short* __restrict__ Ws1b,
                                              const int* __restrict__ tokslot,
                                              const float* __restrict__ wroute,
                                              const int* __restrict__ cnt,
                                              unsigned short* __restrict__ act_r,
                                              unsigned short* __restrict__ acts) {
    __shared__ alignas(16) unsigned short As[2][128 * 32];   // 8KB x2
    __shared__ alignas(16) unsigned short Bs[2][128 * 32];   // 8KB x2
    const int tid = threadIdx.x, lane = tid & 63, w = tid >> 6;
    const int mt = blockIdx.x / 12, ht = blockIdx.x % 12;
    const int h0 = ht * 64;

    int e, m0;
    if (mt < 32) { e = 8 + (mt >> 4); m0 = (mt & 15) * 128; }
    else {
        int rmt = mt - 32;
        int pre = 0, sel = -1, base = 0;
        for (int ee = 0; ee < 8; ee++) {
            int til = (cnt[ee * 16] + 127) >> 7;
            if (sel < 0 && rmt < pre + til) { sel = ee; base = pre; }
            pre += til;
        }
        if (sel < 0) return;
        e = sel; m0 = (rmt - base) * 128;
    }
    const int Te = (e < 8) ? cnt[e * 16] : 2048;
    const unsigned short* Bp = (e < 8) ? (W1b + (size_t)e * 1536 * 1024)
                                       : (Ws1b + (size_t)(e - 8) * 768 * 1024);
    const int gOff = (e < 8) ? 768 : 1536;

    int aoff[4], boff[4];
    for (int q = 0; q < 4; q++) {
        int row = q * 32 + (tid >> 2);
        int p = tid & 3;
        int sw = (row & 3) ^ ((row >> 2) & 3);
        int ko = ((p ^ sw) << 3);
        int idx = m0 + row;
        int tk = (e < 8) ? ((idx < Te) ? tokslot[e * 2048 + idx] : 0) : idx;
        aoff[q] = tk * 1024 + ko;
        int grow = (row < 64) ? (h0 + row) : (gOff + h0 + row - 64);
        boff[q] = grow * 1024 + ko;
    }

    f32x4 accy[4][4], accg[4][4];
    for (int i = 0; i < 4; i++)
        for (int j = 0; j < 4; j++) {
            accy[i][j] = (f32x4){0.f, 0.f, 0.f, 0.f};
            accg[i][j] = (f32x4){0.f, 0.f, 0.f, 0.f};
        }

    for (int q = 0; q < 4; q++) {                 // prologue: stage iter 0 into buf 0
        ldst16(xb + aoff[q], &As[0][(q * 128 + tid) * 8]);
        ldst16(Bp + boff[q], &Bs[0][(q * 128 + tid) * 8]);
    }

    const int cq = lane >> 4, lm = lane & 15;
    for (int it = 0; it < 32; it++) {
        const int bsel = it & 1;
        __syncthreads();                           // stage(it) complete, buf free
        if (it + 1 < 32) {                         // prefetch next stage
            int k0 = (it + 1) * 32, nb = bsel ^ 1;
            for (int q = 0; q < 4; q++) {
                ldst16(xb + aoff[q] + k0, &As[nb][(q * 128 + tid) * 8]);
                ldst16(Bp + boff[q] + k0, &Bs[nb][(q * 128 + tid) * 8]);
            }
        }
        bf16x8 a[4], by[4], bg[4];
        for (int i = 0; i < 4; i++) {
            int r = 64 * w + 16 * i + lm;
            int s = (r & 3) ^ ((r >> 2) & 3);
            a[i] = *(const bf16x8*)&As[bsel][r * 32 + ((cq ^ s) << 3)];
        }
        for (int j = 0; j < 4; j++) {
            int r = 16 * j + lm;
            int s = (r & 3) ^ ((r >> 2) & 3);
            by[j] = *(const bf16x8*)&Bs[bsel][r * 32 + ((cq ^ s) << 3)];
            int rg = 64 + r;
            int s2 = (rg & 3) ^ ((rg >> 2) & 3);
            bg[j] = *(const bf16x8*)&Bs[bsel][rg * 32 + ((cq ^ s2) << 3)];
        }
        for (int i = 0; i < 4; i++)
            for (int j = 0; j < 4; j++) {
                accy[i][j] = __builtin_amdgcn_mfma_f32_16x16x32_bf16(a[i], by[j], accy[i][j], 0, 0, 0);
                accg[i][j] = __builtin_amdgcn_mfma_f32_16x16x32_bf16(a[i], bg[j], accg[i][j], 0, 0, 0);
            }
    }

    for (int i = 0; i < 4; i++)
        for (int r2 = 0; r2 < 4; r2++) {
            int irow = m0 + 64 * w + 16 * i + ((lane >> 4) << 2) + r2;
            if (irow >= Te) continue;
            float swt = (e < 8) ? wroute[e * 2048 + irow] : 1.0f;
            unsigned short* dst = (e < 8)
                ? (act_r + ((size_t)e * 2048 + irow) * 768)
                : (acts + (size_t)irow * 1536 + (size_t)(e - 8) * 768);
            for (int j = 0; j < 4; j++) {
                float y = accy[i][j][r2], g = accg[i][j][r2];
                float sg = g / (1.0f + __expf(-g));
                dst[h0 + 16 * j + lm] = f2b(swt * y * sg);
            }
        }
}

// ---------- fc2: block = 2 waves, tile M128 x N128, BK=32 dbuf, atomicAdd into out ----
// Grid 448 = 56 mt x 8 nt. Slots: mt 0..15 = shared (K=1536, launched first for tail
// balance), 16.. = routed (K=768).
__global__ __launch_bounds__(128) void k_fc2u(const unsigned short* __restrict__ act_r,
                                              const unsigned short* __restrict__ acts,
                                              const unsigned short* __restrict__ W2b,
                                              const unsigned short* __restrict__ Ws2b,
                                              const int* __restrict__ tokslot,
                                              const int* __restrict__ cnt,
                                              float* __restrict__ out) {
    __shared__ alignas(16) unsigned short As[2][128 * 32];
    __shared__ alignas(16) unsigned short Bs[2][128 * 32];
    const int tid = threadIdx.x, lane = tid & 63, w = tid >> 6;
    const int mt = blockIdx.x >> 3, nt = blockIdx.x & 7;
    const int n0 = nt * 128;

    int e, m0, K, astride, bstride, Te;
    const unsigned short *Ab, *Bb;
    if (mt < 16) {
        e = 8; m0 = mt * 128; K = 1536; astride = 1536; bstride = 1536; Te = 2048;
        Ab = acts; Bb = Ws2b;
    } else {
        int rmt = mt - 16;
        int pre = 0, sel = -1, base = 0;
        for (int ee = 0; ee < 8; ee++) {
            int til = (cnt[ee * 16] + 127) >> 7;
            if (sel < 0 && rmt < pre + til) { sel = ee; base = pre; }
            pre += til;
        }
        if (sel < 0) return;
        e = sel; m0 = (rmt - base) * 128; K = 768; astride = 768; bstride = 768;
        Te = cnt[e * 16];
        Ab = act_r + (size_t)e * 2048 * 768;
        Bb = W2b + (size_t)e * 1024 * 768;
    }

    int aoff[4], boff[4];
    for (int q = 0; q < 4; q++) {
        int row = q * 32 + (tid >> 2);
        int p = tid & 3;
        int sw = (row & 3) ^ ((row >> 2) & 3);
        int ko = ((p ^ sw) << 3);
        aoff[q] = (m0 + row) * astride + ko;
        boff[q] = (n0 + row) * bstride + ko;
    }

    f32x4 acc[4][8];
    for (int i = 0; i < 4; i++)
        for (int j = 0; j < 8; j++) acc[i][j] = (f32x4){0.f, 0.f, 0.f, 0.f};

    for (int q = 0; q < 4; q++) {
        ldst16(Ab + aoff[q], &As[0][(q * 128 + tid) * 8]);
        ldst16(Bb + boff[q], &Bs[0][(q * 128 + tid) * 8]);
    }

    const int cq = lane >> 4, lm = lane & 15;
    const int niter = K >> 5;
    for (int it = 0; it < niter; it++) {
        const int bsel = it & 1;
        __syncthreads();
        if (it + 1 < niter) {
            int k0 = (it + 1) * 32, nb = bsel ^ 1;
            for (int q = 0; q < 4; q++) {
                ldst16(Ab + aoff[q] + k0, &As[nb][(q * 128 + tid) * 8]);
                ldst16(Bb + boff[q] + k0, &Bs[nb][(q * 128 + tid) * 8]);
            }
        }
        bf16x8 a[4], bfr[8];
        for (int i = 0; i < 4; i++) {
            int r = 64 * w + 16 * i + lm;
            int s = (r & 3) ^ ((r >> 2) & 3);
            a[i] = *(const bf16x8*)&As[bsel][r * 32 + ((cq ^ s) << 3)];
        }
        for (int j = 0; j < 8; j++) {
            int r = 16 * j + lm;
            int s = (r & 3) ^ ((r >> 2) & 3);
            bfr[j] = *(const bf16x8*)&Bs[bsel][r * 32 + ((cq ^ s) << 3)];
        }
        for (int i = 0; i < 4; i++)
            for (int j = 0; j < 8; j++)
                acc[i][j] = __builtin_amdgcn_mfma_f32_16x16x32_bf16(a[i], bfr[j], acc[i][j], 0, 0, 0);
    }

    for (int i = 0; i < 4; i++)
        for (int r2 = 0; r2 < 4; r2++) {
            int irow = m0 + 64 * w + 16 * i + ((lane >> 4) << 2) + r2;
            if (irow >= Te) continue;
            int t = (e < 8) ? tokslot[e * 2048 + irow] : irow;
            for (int j = 0; j < 8; j++) {
                int col = n0 + 16 * j + lm;
                atomicAdd(out + (size_t)t * 1024 + col, acc[i][j][r2]);
            }
        }
}

extern "C" void kernel_launch(void* const* d_in, const int* in_sizes, int n_in,
                              void* d_out, int out_size, void* d_ws, size_t ws_size,
                              hipStream_t stream) {
    const float* x   = (const float*)d_in[0];
    const float* gw  = (const float*)d_in[1];
    const float* W1  = (const float*)d_in[2];
    const float* W2  = (const float*)d_in[3];
    const float* Ws1 = (const float*)d_in[4];
    const float* Ws2 = (const float*)d_in[5];
    float* out = (float*)d_out;

    char* ws = (char*)d_ws;
    unsigned short* xb    = (unsigned short*)(ws + 0);          //  4,194,304
    unsigned short* W1b   = (unsigned short*)(ws + 4194304);    // 25,165,824
    unsigned short* Ws1b  = (unsigned short*)(ws + 29360128);   //  6,291,456
    unsigned short* W2b   = (unsigned short*)(ws + 35651584);   // 12,582,912
    unsigned short* Ws2b  = (unsigned short*)(ws + 48234496);   //  3,145,728
    unsigned short* act_r = (unsigned short*)(ws + 51380224);   // 25,165,824 (8x2048x768)
    unsigned short* acts  = (unsigned short*)(ws + 76546048);   //  6,291,456 (2048x1536)
    int*            tokslot = (int*)(ws + 82837504);            //     65,536 (8x2048)
    float*          wroute  = (float*)(ws + 82903040);          //     65,536
    int*            cnt     = (int*)(ws + 82968576);            //        512 (8x16 ints)

    hipMemsetAsync(cnt, 0, 512, stream);
    k_convgate<<<13568, 256, 0, stream>>>(x, gw, W1, Ws1, W2, Ws2,
                                          xb, W1b, Ws1b, W2b, Ws2b,
                                          tokslot, wroute, cnt, out);
    k_fc1u<<<864, 128, 0, stream>>>(xb, W1b, Ws1b, tokslot, wroute, cnt, act_r, acts);
    k_fc2u<<<448, 128, 0, stream>>>(act_r, acts, W2b, Ws2b, tokslot, cnt, out);
}

// Round 9
// 237.641 us; speedup vs baseline: 1.2672x; 1.2672x over previous
//
#include <hip/hip_runtime.h>
#include <hip/hip_bf16.h>

// Sparse MoE: T=2048, D=1024, E=8 routed (H=768, top-2) + shared GatedMLP (1536 hidden)
// decomposed into 2 pseudo-experts of routed shape -> 10 uniform experts.
// R9 = R7 structure (best: 235us) + co-residency fixes:
//   fc1: BK=32, LDS 16KB total (m97 shape; up to 6 blocks/CU), 64B-row swizzle (r>>1)&3
//   fc2: BK=64, LDS 24KB, proven 128B-row swizzle c^(r&7), shared(K=1536) tiles first
//   conv: 2880 blocks x 4 cvt8 each. 3 kernels + 512B memset.

typedef short bf16x8 __attribute__((ext_vector_type(8)));
typedef float f32x4 __attribute__((ext_vector_type(4)));

__device__ __forceinline__ unsigned short f2b(float f) {
    __hip_bfloat16 h = __float2bfloat16(f);
    return *reinterpret_cast<unsigned short*>(&h);
}

__device__ __forceinline__ void ldst16(const unsigned short* g, unsigned short* l) {
    __builtin_amdgcn_global_load_lds(
        (const __attribute__((address_space(1))) unsigned int*)g,
        (__attribute__((address_space(3))) unsigned int*)l, 16, 0, 0);
}

__device__ __forceinline__ void cvt8(const float* s, unsigned short* d, int j) {
    const float4* sp = reinterpret_cast<const float4*>(s) + (size_t)j * 2;
    float4 v0 = sp[0], v1 = sp[1];
    union { unsigned short u[8]; uint4 v; } o;
    o.u[0]=f2b(v0.x); o.u[1]=f2b(v0.y); o.u[2]=f2b(v0.z); o.u[3]=f2b(v0.w);
    o.u[4]=f2b(v1.x); o.u[5]=f2b(v1.y); o.u[6]=f2b(v1.z); o.u[7]=f2b(v1.w);
    *(reinterpret_cast<uint4*>(d) + j) = o.v;
}

// ------- merged: weight conversion (blocks 0..2879, 4 cvt8 each) + gate (2880..4927) --
__global__ __launch_bounds__(256) void k_convgate(const float* __restrict__ x,
                                                  const float* __restrict__ gw,
                                                  const float* __restrict__ W1,
                                                  const float* __restrict__ Ws1,
                                                  const float* __restrict__ W2,
                                                  const float* __restrict__ Ws2,
                                                  unsigned short* __restrict__ xb,
                                                  unsigned short* __restrict__ W1b,
                                                  unsigned short* __restrict__ Ws1b,
                                                  unsigned short* __restrict__ W2b,
                                                  unsigned short* __restrict__ Ws2b,
                                                  int* __restrict__ tokslot,
                                                  float* __restrict__ wroute,
                                                  int* __restrict__ cnt,
                                                  float* __restrict__ out) {
    __shared__ float red[4][8];
    __shared__ float sc[8];
    const int b = blockIdx.x, tid = threadIdx.x;
    if (b < 2880) {
        for (int q = 0; q < 4; q++) {
            int i = b * 1024 + q * 256 + tid;       // 2880*1024 == 2949120 exactly
            if (i < 1572864)       cvt8(W1,  W1b,  i);
            else if (i < 1966080)  cvt8(Ws1, Ws1b, i - 1572864);
            else if (i < 2752512)  cvt8(W2,  W2b,  i - 1966080);
            else                   cvt8(Ws2, Ws2b, i - 2752512);
        }
        return;
    }
    const int t = b - 2880;
    const int lane = tid & 63, w = tid >> 6;

    float4 v = reinterpret_cast<const float4*>(x + (size_t)t * 1024)[tid];
    union { unsigned short u[4]; } o;
    o.u[0]=f2b(v.x); o.u[1]=f2b(v.y); o.u[2]=f2b(v.z); o.u[3]=f2b(v.w);
    reinterpret_cast<ushort4*>(xb + (size_t)t * 1024)[tid] = *(ushort4*)o.u;

    float p[8];
    for (int e = 0; e < 8; e++) {
        float4 g = reinterpret_cast<const float4*>(gw + (size_t)e * 1024)[tid];
        p[e] = v.x*g.x + v.y*g.y + v.z*g.z + v.w*g.w;
    }
    for (int e = 0; e < 8; e++)
        for (int off = 32; off > 0; off >>= 1) p[e] += __shfl_down(p[e], off, 64);
    if (lane == 0)
        for (int e = 0; e < 8; e++) red[w][e] = p[e];
    __syncthreads();
    if (tid < 8) sc[tid] = red[0][tid] + red[1][tid] + red[2][tid] + red[3][tid];
    __syncthreads();
    if (tid == 0) {
        float m = sc[0];
        for (int e = 1; e < 8; e++) m = fmaxf(m, sc[e]);
        float ex[8], sum = 0.f;
        for (int e = 0; e < 8; e++) { ex[e] = expf(sc[e] - m); sum += ex[e]; }
        float inv = 1.f / sum;
        int i1 = 0;
        for (int e = 1; e < 8; e++) if (sc[e] > sc[i1]) i1 = e;
        int i2 = -1; float s2 = -1e30f;
        for (int e = 0; e < 8; e++) if (e != i1 && sc[e] > s2) { s2 = sc[e]; i2 = e; }
        int p1 = atomicAdd(&cnt[i1 * 16], 1);          // 64B-padded counters
        tokslot[i1 * 2048 + p1] = t; wroute[i1 * 2048 + p1] = ex[i1] * inv;
        int p2 = atomicAdd(&cnt[i2 * 16], 1);
        tokslot[i2 * 2048 + p2] = t; wroute[i2 * 2048 + p2] = ex[i2] * inv;
    }
    reinterpret_cast<float4*>(out + (size_t)t * 1024)[tid] = (float4){0.f, 0.f, 0.f, 0.f};
}

// ---------- fc1: 10 experts, M=128 tok x N=64 h (y+g = 128 B-rows), BK=32 ----------
// Grid 864 = 72 mt x 12 ht. LDS 8KB+8KB. 64B rows: swizzle s(r)=(r>>1)&3 (2-way free).
__global__ __launch_bounds__(256) void k_fc1u(const unsigned short* __restrict__ xb,
                                              const unsigned short* __restrict__ W1b,
                                              const unsigned short* __restrict__ Ws1b,
                                              const int* __restrict__ tokslot,
                                              const float* __restrict__ wroute,
                                              const int* __restrict__ cnt,
                                              unsigned short* __restrict__ act_r,
                                              unsigned short* __restrict__ acts) {
    __shared__ alignas(16) unsigned short As[128 * 32];   // 8KB
    __shared__ alignas(16) unsigned short Bs[128 * 32];   // 8KB: rows 0..63 y, 64..127 g
    const int tid = threadIdx.x, lane = tid & 63, w = tid >> 6;
    const int wr = w >> 1, wc = w & 1;
    const int mt = blockIdx.x / 12, ht = blockIdx.x % 12;
    const int h0 = ht * 64;

    int pre = 0, sel = -1, base = 0;
    for (int ee = 0; ee < 10; ee++) {
        int til = (ee < 8) ? ((cnt[ee * 16] + 127) >> 7) : 16;
        if (sel < 0 && mt < pre + til) { sel = ee; base = pre; }
        pre += til;
    }
    if (sel < 0) return;
    const int e = sel, m0 = (mt - base) * 128;
    const int Te = (e < 8) ? cnt[e * 16] : 2048;
    const unsigned short* Bp = (e < 8) ? (W1b + (size_t)e * 1536 * 1024)
                                       : (Ws1b + (size_t)(e - 8) * 768 * 1024);
    const int gOff = (e < 8) ? 768 : 1536;

    int aoff[2], boff[2];
    for (int q = 0; q < 2; q++) {
        int ch = q * 256 + tid;
        int row = ch >> 2, c = ch & 3;
        int ko = ((c ^ ((row >> 1) & 3)) << 3);
        int idx = m0 + row;
        int tk = (e < 8) ? ((idx < Te) ? tokslot[e * 2048 + idx] : 0) : idx;
        aoff[q] = tk * 1024 + ko;
        int grow = (row < 64) ? (h0 + row) : (gOff + h0 + row - 64);
        boff[q] = grow * 1024 + ko;
    }

    f32x4 accy[4][2], accg[4][2];
    for (int i = 0; i < 4; i++)
        for (int j = 0; j < 2; j++) {
            accy[i][j] = (f32x4){0.f, 0.f, 0.f, 0.f};
            accg[i][j] = (f32x4){0.f, 0.f, 0.f, 0.f};
        }

    const int cq = lane >> 4, lm = lane & 15;
    for (int k0 = 0; k0 < 1024; k0 += 32) {
        for (int q = 0; q < 2; q++) {
            ldst16(xb + aoff[q] + k0, As + (q * 256 + tid) * 8);
            ldst16(Bp + boff[q] + k0, Bs + (q * 256 + tid) * 8);
        }
        __syncthreads();
        bf16x8 a[4], by[2], bg[2];
        for (int i = 0; i < 4; i++) {
            int r = 64 * wr + 16 * i + lm;
            a[i] = *(const bf16x8*)&As[r * 32 + ((cq ^ ((r >> 1) & 3)) << 3)];
        }
        for (int j = 0; j < 2; j++) {
            int ry = 32 * wc + 16 * j + lm;
            by[j] = *(const bf16x8*)&Bs[ry * 32 + ((cq ^ ((ry >> 1) & 3)) << 3)];
            int rg = 64 + ry;
            bg[j] = *(const bf16x8*)&Bs[rg * 32 + ((cq ^ ((rg >> 1) & 3)) << 3)];
        }
        for (int i = 0; i < 4; i++)
            for (int j = 0; j < 2; j++) {
                accy[i][j] = __builtin_amdgcn_mfma_f32_16x16x32_bf16(a[i], by[j], accy[i][j], 0, 0, 0);
                accg[i][j] = __builtin_amdgcn_mfma_f32_16x16x32_bf16(a[i], bg[j], accg[i][j], 0, 0, 0);
            }
        __syncthreads();
    }

    for (int i = 0; i < 4; i++)
        for (int r2 = 0; r2 < 4; r2++) {
            int irow = m0 + 64 * wr + 16 * i + ((lane >> 4) << 2) + r2;
            if (irow >= Te) continue;
            float sw = (e < 8) ? wroute[e * 2048 + irow] : 1.0f;
            unsigned short* dst = (e < 8)
                ? (act_r + ((size_t)e * 2048 + irow) * 768)
                : (acts + (size_t)irow * 1536 + (size_t)(e - 8) * 768);
            for (int j = 0; j < 2; j++) {
                float y = accy[i][j][r2], g = accg[i][j][r2];
                float sg = g / (1.0f + __expf(-g));
                dst[h0 + 32 * wc + 16 * j + lm] = f2b(sw * y * sg);
            }
        }
}

// ------- fc2: M=128 x N=64, BK=64, LDS 24KB; shared (K=1536) tiles first --------
// Grid 896 = 56 mt x 16 nt. atomicAdd into out (zeroed by gate).
__global__ __launch_bounds__(256) void k_fc2u(const unsigned short* __restrict__ act_r,
                                              const unsigned short* __restrict__ acts,
                                              const unsigned short* __restrict__ W2b,
                                              const unsigned short* __restrict__ Ws2b,
                                              const int* __restrict__ tokslot,
                                              const int* __restrict__ cnt,
                                              float* __restrict__ out) {
    __shared__ alignas(16) unsigned short As[128 * 64];   // 16KB
    __shared__ alignas(16) unsigned short Bs[64 * 64];    // 8KB
    const int tid = threadIdx.x, lane = tid & 63, w = tid >> 6;
    const int wr = w >> 1, wc = w & 1;
    const int mt = blockIdx.x >> 4, nt = blockIdx.x & 15;
    const int n0 = nt * 64;

    int e, m0, K, astride, bstride, Te;
    const unsigned short *Ab, *Bb;
    if (mt < 16) {
        e = 8; m0 = mt * 128; K = 1536; astride = 1536; bstride = 1536; Te = 2048;
        Ab = acts; Bb = Ws2b;
    } else {
        int rmt = mt - 16;
        int pre = 0, sel = -1, base = 0;
        for (int ee = 0; ee < 8; ee++) {
            int til = (cnt[ee * 16] + 127) >> 7;
            if (sel < 0 && rmt < pre + til) { sel = ee; base = pre; }
            pre += til;
        }
        if (sel < 0) return;
        e = sel; m0 = (rmt - base) * 128; K = 768; astride = 768; bstride = 768;
        Te = cnt[e * 16];
        Ab = act_r + (size_t)e * 2048 * 768;
        Bb = W2b + (size_t)e * 1024 * 768;
    }

    int aoff[4], boff[2];
    for (int q = 0; q < 4; q++) {
        int ch = q * 256 + tid;
        int row = ch >> 3, c = ch & 7;
        aoff[q] = (m0 + row) * astride + ((c ^ (row & 7)) << 3);
    }
    for (int q = 0; q < 2; q++) {
        int ch = q * 256 + tid;
        int row = ch >> 3, c = ch & 7;
        boff[q] = (n0 + row) * bstride + ((c ^ (row & 7)) << 3);
    }

    f32x4 acc[4][2];
    for (int i = 0; i < 4; i++)
        for (int j = 0; j < 2; j++) acc[i][j] = (f32x4){0.f, 0.f, 0.f, 0.f};

    const int lm = lane & 15;
    for (int k0 = 0; k0 < K; k0 += 64) {
        for (int q = 0; q < 4; q++) ldst16(Ab + aoff[q] + k0, As + (q * 256 + tid) * 8);
        for (int q = 0; q < 2; q++) ldst16(Bb + boff[q] + k0, Bs + (q * 256 + tid) * 8);
        __syncthreads();
        for (int kh = 0; kh < 2; kh++) {
            const int cq = kh * 4 + (lane >> 4);
            bf16x8 a[4], b[2];
            for (int i = 0; i < 4; i++) {
                int r = 64 * wr + 16 * i + lm;
                a[i] = *(const bf16x8*)&As[r * 64 + ((cq ^ (r & 7)) << 3)];
            }
            for (int j = 0; j < 2; j++) {
                int rb = 32 * wc + 16 * j + lm;
                b[j] = *(const bf16x8*)&Bs[rb * 64 + ((cq ^ (rb & 7)) << 3)];
            }
            for (int i = 0; i < 4; i++)
                for (int j = 0; j < 2; j++)
                    acc[i][j] = __builtin_amdgcn_mfma_f32_16x16x32_bf16(a[i], b[j], acc[i][j], 0, 0, 0);
        }
        __syncthreads();
    }

    for (int i = 0; i < 4; i++)
        for (int r2 = 0; r2 < 4; r2++) {
            int irow = m0 + 64 * wr + 16 * i + ((lane >> 4) << 2) + r2;
            if (irow >= Te) continue;
            int t = (e < 8) ? tokslot[e * 2048 + irow] : irow;
            for (int j = 0; j < 2; j++) {
                int col = n0 + 32 * wc + 16 * j + lm;
                atomicAdd(out + (size_t)t * 1024 + col, acc[i][j][r2]);
            }
        }
}

extern "C" void kernel_launch(void* const* d_in, const int* in_sizes, int n_in,
                              void* d_out, int out_size, void* d_ws, size_t ws_size,
                              hipStream_t stream) {
    const float* x   = (const float*)d_in[0];
    const float* gw  = (const float*)d_in[1];
    const float* W1  = (const float*)d_in[2];
    const float* W2  = (const float*)d_in[3];
    const float* Ws1 = (const float*)d_in[4];
    const float* Ws2 = (const float*)d_in[5];
    float* out = (float*)d_out;

    char* ws = (char*)d_ws;
    unsigned short* xb    = (unsigned short*)(ws + 0);          //  4,194,304
    unsigned short* W1b   = (unsigned short*)(ws + 4194304);    // 25,165,824
    unsigned short* Ws1b  = (unsigned short*)(ws + 29360128);   //  6,291,456
    unsigned short* W2b   = (unsigned short*)(ws + 35651584);   // 12,582,912
    unsigned short* Ws2b  = (unsigned short*)(ws + 48234496);   //  3,145,728
    unsigned short* act_r = (unsigned short*)(ws + 51380224);   // 25,165,824 (8x2048x768)
    unsigned short* acts  = (unsigned short*)(ws + 76546048);   //  6,291,456 (2048x1536)
    int*            tokslot = (int*)(ws + 82837504);            //     65,536 (8x2048)
    float*          wroute  = (float*)(ws + 82903040);          //     65,536
    int*            cnt     = (int*)(ws + 82968576);            //        512 (8x16 ints)

    hipMemsetAsync(cnt, 0, 512, stream);
    k_convgate<<<4928, 256, 0, stream>>>(x, gw, W1, Ws1, W2, Ws2,
                                         xb, W1b, Ws1b, W2b, Ws2b,
                                         tokslot, wroute, cnt, out);
    k_fc1u<<<864, 256, 0, stream>>>(xb, W1b, Ws1b, tokslot, wroute, cnt, act_r, acts);
    k_fc2u<<<896, 256, 0, stream>>>(act_r, acts, W2b, Ws2b, tokslot, cnt, out);
}